// Round 1
// baseline (1163.762 us; speedup 1.0000x reference)
//
#include <hip/hip_runtime.h>

// COO scatter-add: out[row[i], :] += mat[col[i], :]
// NT=NC=100000, NNZ=640000, D=128, fp32.
// One 32-lane group per nonzero; each lane handles a float4 (4 columns).

#define NNZ_CONST 640000
#define D_CONST 128

__global__ __launch_bounds__(256) void scatter_add_kernel(
    const float* __restrict__ mat,
    const int* __restrict__ row,
    const int* __restrict__ col,
    float* __restrict__ out) {
    int gid = blockIdx.x * blockDim.x + threadIdx.x;
    int nz = gid >> 5;          // one nonzero per 32 lanes
    int lane = gid & 31;        // lane covers 4 floats -> 32*4 = 128 = D
    if (nz >= NNZ_CONST) return;

    int r = row[nz];
    int c = col[nz];

    const float4 v =
        reinterpret_cast<const float4*>(mat + (size_t)c * D_CONST)[lane];
    float* o = out + (size_t)r * D_CONST + (size_t)lane * 4;

    atomicAdd(o + 0, v.x);
    atomicAdd(o + 1, v.y);
    atomicAdd(o + 2, v.z);
    atomicAdd(o + 3, v.w);
}

extern "C" void kernel_launch(void* const* d_in, const int* in_sizes, int n_in,
                              void* d_out, int out_size, void* d_ws, size_t ws_size,
                              hipStream_t stream) {
    const float* mat = (const float*)d_in[0];
    const int* row   = (const int*)d_in[1];
    const int* col   = (const int*)d_in[2];
    float* out = (float*)d_out;

    // d_out is poisoned 0xAA before every launch -> zero it first.
    hipMemsetAsync(out, 0, (size_t)out_size * sizeof(float), stream);

    const long long total_threads = (long long)NNZ_CONST * 32;
    const int block = 256;
    const int grid = (int)((total_threads + block - 1) / block);
    scatter_add_kernel<<<grid, block, 0, stream>>>(mat, row, col, out);
}

// Round 2
// 211.620 us; speedup vs baseline: 5.4993x; 5.4993x over previous
//
#include <hip/hip_runtime.h>

// COO scatter-add via counting sort + segment sum (atomic-free output).
// out[row[i], :] += mat[col[i], :]   NC=NT=100000, NNZ=640000, D=128, fp32.

#define NC_CONST 100000
#define NNZ_CONST 640000
#define D_CONST 128
#define SCAN_BLK 256
#define NBLK ((NC_CONST + SCAN_BLK - 1) / SCAN_BLK)   // 391

// ---------- Phase 1: histogram of rows ----------
__global__ __launch_bounds__(256) void hist_kernel(
    const int* __restrict__ row, int* __restrict__ cnt) {
    int i = blockIdx.x * blockDim.x + threadIdx.x;
    if (i < NNZ_CONST) atomicAdd(&cnt[row[i]], 1);
}

// ---------- Phase 2a: per-block reduce of counts ----------
__global__ __launch_bounds__(SCAN_BLK) void scan_reduce_kernel(
    const int* __restrict__ cnt, int* __restrict__ blocksums) {
    __shared__ int lds[SCAN_BLK];
    int i = blockIdx.x * SCAN_BLK + threadIdx.x;
    int v = (i < NC_CONST) ? cnt[i] : 0;
    lds[threadIdx.x] = v;
    __syncthreads();
    for (int s = SCAN_BLK / 2; s > 0; s >>= 1) {
        if (threadIdx.x < s) lds[threadIdx.x] += lds[threadIdx.x + s];
        __syncthreads();
    }
    if (threadIdx.x == 0) blocksums[blockIdx.x] = lds[0];
}

// ---------- Phase 2b: single-block scan of block sums ----------
__global__ __launch_bounds__(512) void scan_spine_kernel(
    const int* __restrict__ blocksums, int* __restrict__ blockoffs) {
    __shared__ int lds[512];
    int t = threadIdx.x;
    int v = (t < NBLK) ? blocksums[t] : 0;
    lds[t] = v;
    __syncthreads();
    // Hillis-Steele inclusive scan over 512
    for (int s = 1; s < 512; s <<= 1) {
        int add = (t >= s) ? lds[t - s] : 0;
        __syncthreads();
        lds[t] += add;
        __syncthreads();
    }
    if (t < NBLK) blockoffs[t] = lds[t] - v;  // exclusive
}

// ---------- Phase 2c: per-block scan + write offsets & cursors ----------
__global__ __launch_bounds__(SCAN_BLK) void scan_final_kernel(
    const int* __restrict__ cnt, const int* __restrict__ blockoffs,
    int* __restrict__ offs, int* __restrict__ cursor) {
    __shared__ int lds[SCAN_BLK];
    int i = blockIdx.x * SCAN_BLK + threadIdx.x;
    int t = threadIdx.x;
    int v = (i < NC_CONST) ? cnt[i] : 0;
    lds[t] = v;
    __syncthreads();
    for (int s = 1; s < SCAN_BLK; s <<= 1) {
        int add = (t >= s) ? lds[t - s] : 0;
        __syncthreads();
        lds[t] += add;
        __syncthreads();
    }
    int off = blockoffs[blockIdx.x] + lds[t] - v;  // exclusive global offset
    if (i < NC_CONST) {
        offs[i] = off;
        cursor[i] = off;
        if (i == NC_CONST - 1) offs[NC_CONST] = off + v;
    }
}

// ---------- Phase 3: placement (counting-sort scatter of col indices) ----
__global__ __launch_bounds__(256) void place_kernel(
    const int* __restrict__ row, const int* __restrict__ col,
    int* __restrict__ cursor, int* __restrict__ sorted_col) {
    int i = blockIdx.x * blockDim.x + threadIdx.x;
    if (i < NNZ_CONST) {
        int p = atomicAdd(&cursor[row[i]], 1);
        sorted_col[p] = col[i];
    }
}

// ---------- Phase 4: segment sum, one 32-lane group per output row -------
__global__ __launch_bounds__(256) void segsum_kernel(
    const float* __restrict__ mat, const int* __restrict__ offs,
    const int* __restrict__ sorted_col, float* __restrict__ out) {
    int g = blockIdx.x * 8 + (threadIdx.x >> 5);  // row index
    int lane = threadIdx.x & 31;                  // covers 4 floats
    if (g >= NC_CONST) return;
    int beg = offs[g];
    int end = offs[g + 1];
    float ax = 0.f, ay = 0.f, az = 0.f, aw = 0.f;
    for (int j = beg; j < end; ++j) {
        int c = sorted_col[j];
        const float4 v =
            reinterpret_cast<const float4*>(mat + (size_t)c * D_CONST)[lane];
        ax += v.x; ay += v.y; az += v.z; aw += v.w;
    }
    float4 r; r.x = ax; r.y = ay; r.z = az; r.w = aw;
    reinterpret_cast<float4*>(out + (size_t)g * D_CONST)[lane] = r;
}

// ---------- Fallback: direct atomic scatter (if ws too small) ------------
__global__ __launch_bounds__(256) void scatter_add_kernel(
    const float* __restrict__ mat, const int* __restrict__ row,
    const int* __restrict__ col, float* __restrict__ out) {
    int gid = blockIdx.x * blockDim.x + threadIdx.x;
    int nz = gid >> 5;
    int lane = gid & 31;
    if (nz >= NNZ_CONST) return;
    int r = row[nz];
    int c = col[nz];
    const float4 v =
        reinterpret_cast<const float4*>(mat + (size_t)c * D_CONST)[lane];
    float* o = out + (size_t)r * D_CONST + (size_t)lane * 4;
    atomicAdd(o + 0, v.x);
    atomicAdd(o + 1, v.y);
    atomicAdd(o + 2, v.z);
    atomicAdd(o + 3, v.w);
}

extern "C" void kernel_launch(void* const* d_in, const int* in_sizes, int n_in,
                              void* d_out, int out_size, void* d_ws, size_t ws_size,
                              hipStream_t stream) {
    const float* mat = (const float*)d_in[0];
    const int* row   = (const int*)d_in[1];
    const int* col   = (const int*)d_in[2];
    float* out = (float*)d_out;

    // Workspace layout (ints)
    size_t need = (size_t)(NC_CONST        // cnt
                 + NC_CONST + 1            // offs
                 + NC_CONST                // cursor
                 + NNZ_CONST               // sorted_col
                 + NBLK                    // blocksums
                 + NBLK) * sizeof(int);    // blockoffs

    if (ws_size < need) {
        // Fallback: atomic scatter (correct, slower).
        hipMemsetAsync(out, 0, (size_t)out_size * sizeof(float), stream);
        const long long total = (long long)NNZ_CONST * 32;
        scatter_add_kernel<<<(int)((total + 255) / 256), 256, 0, stream>>>(
            mat, row, col, out);
        return;
    }

    int* cnt        = (int*)d_ws;
    int* offs       = cnt + NC_CONST;
    int* cursor     = offs + NC_CONST + 1;
    int* sorted_col = cursor + NC_CONST;
    int* blocksums  = sorted_col + NNZ_CONST;
    int* blockoffs  = blocksums + NBLK;

    hipMemsetAsync(cnt, 0, (size_t)NC_CONST * sizeof(int), stream);

    hist_kernel<<<(NNZ_CONST + 255) / 256, 256, 0, stream>>>(row, cnt);
    scan_reduce_kernel<<<NBLK, SCAN_BLK, 0, stream>>>(cnt, blocksums);
    scan_spine_kernel<<<1, 512, 0, stream>>>(blocksums, blockoffs);
    scan_final_kernel<<<NBLK, SCAN_BLK, 0, stream>>>(cnt, blockoffs, offs, cursor);
    place_kernel<<<(NNZ_CONST + 255) / 256, 256, 0, stream>>>(row, col, cursor, sorted_col);
    segsum_kernel<<<(NC_CONST + 7) / 8, 256, 0, stream>>>(mat, offs, sorted_col, out);
}

// Round 4
// 180.724 us; speedup vs baseline: 6.4394x; 1.1710x over previous
//
#include <hip/hip_runtime.h>

// COO scatter-add: out[row[i], :] += mat[col[i], :]
// NC=NT=100000, NNZ=640000, D=128, fp32.
// Strategy: fixed-capacity row buckets (atomic append) -> segment sum.
// Rows ~ Poisson(6.4); CAP=32 overflow probability ~1e-13 per row, but a
// correct overflow path exists (spill list, folded into segsum).

#define NC_CONST 100000
#define NNZ_CONST 640000
#define D_CONST 128
#define OVF_MAX 65536
#define SCAN_BLK 256
#define NBLK ((NC_CONST + SCAN_BLK - 1) / SCAN_BLK)

typedef float v4f __attribute__((ext_vector_type(4)));  // native vector for nt-store

// ---------------- bucket placement (hist fused: atomicAdd returns slot) ---
template <int CAP>
__global__ __launch_bounds__(256) void place_bucket_kernel(
    const int* __restrict__ row, const int* __restrict__ col,
    int* __restrict__ cnt, int* __restrict__ ovf_cnt,
    int* __restrict__ ovf, int* __restrict__ bucket) {
    int i = blockIdx.x * blockDim.x + threadIdx.x;
    if (i >= NNZ_CONST) return;
    int r = row[i];
    int c = col[i];
    int idx = atomicAdd(&cnt[r], 1);
    if (idx < CAP) {
        bucket[r * CAP + idx] = c;
    } else {
        int o = atomicAdd(ovf_cnt, 1);
        if (o < OVF_MAX) { ovf[2 * o] = r; ovf[2 * o + 1] = c; }
    }
}

// ---------------- segment sum: one 32-lane group per output row ----------
template <int CAP>
__global__ __launch_bounds__(256) void segsum_bucket_kernel(
    const float* __restrict__ mat, const int* __restrict__ cnt,
    const int* __restrict__ ovf_cnt, const int* __restrict__ ovf,
    const int* __restrict__ bucket, float* __restrict__ out) {
    int g = blockIdx.x * 8 + (threadIdx.x >> 5);
    int lane = threadIdx.x & 31;
    if (g >= NC_CONST) return;

    int n = cnt[g];
    if (n > CAP) n = CAP;

    // coalesced load of this row's column indices, broadcast via shfl
    int myc = (lane < n) ? bucket[g * CAP + lane] : 0;

    float ax = 0.f, ay = 0.f, az = 0.f, aw = 0.f;
    for (int j = 0; j < n; ++j) {
        int c = __shfl(myc, j, 32);
        const float4 v =
            reinterpret_cast<const float4*>(mat + (size_t)c * D_CONST)[lane];
        ax += v.x; ay += v.y; az += v.z; aw += v.w;
    }

    // overflow entries (rare-to-never): linear scan of spill list
    int novf = *ovf_cnt;
    if (novf > OVF_MAX) novf = OVF_MAX;
    for (int o = 0; o < novf; ++o) {
        if (ovf[2 * o] == g) {
            int c = ovf[2 * o + 1];
            const float4 v =
                reinterpret_cast<const float4*>(mat + (size_t)c * D_CONST)[lane];
            ax += v.x; ay += v.y; az += v.z; aw += v.w;
        }
    }

    v4f r;
    r.x = ax; r.y = ay; r.z = az; r.w = aw;
    __builtin_nontemporal_store(
        r, reinterpret_cast<v4f*>(out + (size_t)g * D_CONST) + lane);
}

// ================== fallback tier: full counting sort (round-2) ==========
__global__ __launch_bounds__(256) void hist_kernel(
    const int* __restrict__ row, int* __restrict__ cnt) {
    int i = blockIdx.x * blockDim.x + threadIdx.x;
    if (i < NNZ_CONST) atomicAdd(&cnt[row[i]], 1);
}

__global__ __launch_bounds__(SCAN_BLK) void scan_reduce_kernel(
    const int* __restrict__ cnt, int* __restrict__ blocksums) {
    __shared__ int lds[SCAN_BLK];
    int i = blockIdx.x * SCAN_BLK + threadIdx.x;
    int v = (i < NC_CONST) ? cnt[i] : 0;
    lds[threadIdx.x] = v;
    __syncthreads();
    for (int s = SCAN_BLK / 2; s > 0; s >>= 1) {
        if (threadIdx.x < s) lds[threadIdx.x] += lds[threadIdx.x + s];
        __syncthreads();
    }
    if (threadIdx.x == 0) blocksums[blockIdx.x] = lds[0];
}

__global__ __launch_bounds__(512) void scan_spine_kernel(
    const int* __restrict__ blocksums, int* __restrict__ blockoffs) {
    __shared__ int lds[512];
    int t = threadIdx.x;
    int v = (t < NBLK) ? blocksums[t] : 0;
    lds[t] = v;
    __syncthreads();
    for (int s = 1; s < 512; s <<= 1) {
        int add = (t >= s) ? lds[t - s] : 0;
        __syncthreads();
        lds[t] += add;
        __syncthreads();
    }
    if (t < NBLK) blockoffs[t] = lds[t] - v;
}

__global__ __launch_bounds__(SCAN_BLK) void scan_final_kernel(
    const int* __restrict__ cnt, const int* __restrict__ blockoffs,
    int* __restrict__ offs, int* __restrict__ cursor) {
    __shared__ int lds[SCAN_BLK];
    int i = blockIdx.x * SCAN_BLK + threadIdx.x;
    int t = threadIdx.x;
    int v = (i < NC_CONST) ? cnt[i] : 0;
    lds[t] = v;
    __syncthreads();
    for (int s = 1; s < SCAN_BLK; s <<= 1) {
        int add = (t >= s) ? lds[t - s] : 0;
        __syncthreads();
        lds[t] += add;
        __syncthreads();
    }
    int off = blockoffs[blockIdx.x] + lds[t] - v;
    if (i < NC_CONST) {
        offs[i] = off;
        cursor[i] = off;
        if (i == NC_CONST - 1) offs[NC_CONST] = off + v;
    }
}

__global__ __launch_bounds__(256) void place_kernel(
    const int* __restrict__ row, const int* __restrict__ col,
    int* __restrict__ cursor, int* __restrict__ sorted_col) {
    int i = blockIdx.x * blockDim.x + threadIdx.x;
    if (i < NNZ_CONST) {
        int p = atomicAdd(&cursor[row[i]], 1);
        sorted_col[p] = col[i];
    }
}

__global__ __launch_bounds__(256) void segsum_kernel(
    const float* __restrict__ mat, const int* __restrict__ offs,
    const int* __restrict__ sorted_col, float* __restrict__ out) {
    int g = blockIdx.x * 8 + (threadIdx.x >> 5);
    int lane = threadIdx.x & 31;
    if (g >= NC_CONST) return;
    int beg = offs[g];
    int end = offs[g + 1];
    float ax = 0.f, ay = 0.f, az = 0.f, aw = 0.f;
    for (int j = beg; j < end; ++j) {
        int c = sorted_col[j];
        const float4 v =
            reinterpret_cast<const float4*>(mat + (size_t)c * D_CONST)[lane];
        ax += v.x; ay += v.y; az += v.z; aw += v.w;
    }
    float4 r; r.x = ax; r.y = ay; r.z = az; r.w = aw;
    reinterpret_cast<float4*>(out + (size_t)g * D_CONST)[lane] = r;
}

__global__ __launch_bounds__(256) void scatter_add_kernel(
    const float* __restrict__ mat, const int* __restrict__ row,
    const int* __restrict__ col, float* __restrict__ out) {
    int gid = blockIdx.x * blockDim.x + threadIdx.x;
    int nz = gid >> 5;
    int lane = gid & 31;
    if (nz >= NNZ_CONST) return;
    int r = row[nz];
    int c = col[nz];
    const float4 v =
        reinterpret_cast<const float4*>(mat + (size_t)c * D_CONST)[lane];
    float* o = out + (size_t)r * D_CONST + (size_t)lane * 4;
    atomicAdd(o + 0, v.x);
    atomicAdd(o + 1, v.y);
    atomicAdd(o + 2, v.z);
    atomicAdd(o + 3, v.w);
}

// =========================================================================
template <int CAP>
static void launch_bucket_path(const float* mat, const int* row, const int* col,
                               float* out, void* d_ws, hipStream_t stream) {
    int* cnt     = (int*)d_ws;               // NC
    int* ovf_cnt = cnt + NC_CONST;           // 1
    int* ovf     = ovf_cnt + 1;              // 2*OVF_MAX
    int* bucket  = ovf + 2 * OVF_MAX;        // NC*CAP

    // zero cnt + ovf_cnt in one memset (they're contiguous)
    (void)hipMemsetAsync(cnt, 0, (size_t)(NC_CONST + 1) * sizeof(int), stream);

    place_bucket_kernel<CAP><<<(NNZ_CONST + 255) / 256, 256, 0, stream>>>(
        row, col, cnt, ovf_cnt, ovf, bucket);
    segsum_bucket_kernel<CAP><<<(NC_CONST + 7) / 8, 256, 0, stream>>>(
        mat, cnt, ovf_cnt, ovf, bucket, out);
}

extern "C" void kernel_launch(void* const* d_in, const int* in_sizes, int n_in,
                              void* d_out, int out_size, void* d_ws, size_t ws_size,
                              hipStream_t stream) {
    const float* mat = (const float*)d_in[0];
    const int* row   = (const int*)d_in[1];
    const int* col   = (const int*)d_in[2];
    float* out = (float*)d_out;

    const size_t need32 =
        (size_t)(NC_CONST + 1 + 2 * OVF_MAX + (size_t)NC_CONST * 32) * sizeof(int);
    const size_t need16 =
        (size_t)(NC_CONST + 1 + 2 * OVF_MAX + (size_t)NC_CONST * 16) * sizeof(int);
    const size_t need_sort =
        (size_t)(NC_CONST + NC_CONST + 1 + NC_CONST + NNZ_CONST + 2 * NBLK) *
        sizeof(int);

    if (ws_size >= need32) {
        launch_bucket_path<32>(mat, row, col, out, d_ws, stream);
    } else if (ws_size >= need16) {
        launch_bucket_path<16>(mat, row, col, out, d_ws, stream);
    } else if (ws_size >= need_sort) {
        int* cnt        = (int*)d_ws;
        int* offs       = cnt + NC_CONST;
        int* cursor     = offs + NC_CONST + 1;
        int* sorted_col = cursor + NC_CONST;
        int* blocksums  = sorted_col + NNZ_CONST;
        int* blockoffs  = blocksums + NBLK;

        (void)hipMemsetAsync(cnt, 0, (size_t)NC_CONST * sizeof(int), stream);
        hist_kernel<<<(NNZ_CONST + 255) / 256, 256, 0, stream>>>(row, cnt);
        scan_reduce_kernel<<<NBLK, SCAN_BLK, 0, stream>>>(cnt, blocksums);
        scan_spine_kernel<<<1, 512, 0, stream>>>(blocksums, blockoffs);
        scan_final_kernel<<<NBLK, SCAN_BLK, 0, stream>>>(cnt, blockoffs, offs, cursor);
        place_kernel<<<(NNZ_CONST + 255) / 256, 256, 0, stream>>>(row, col, cursor, sorted_col);
        segsum_kernel<<<(NC_CONST + 7) / 8, 256, 0, stream>>>(mat, offs, sorted_col, out);
    } else {
        (void)hipMemsetAsync(out, 0, (size_t)out_size * sizeof(float), stream);
        const long long total = (long long)NNZ_CONST * 32;
        scatter_add_kernel<<<(int)((total + 255) / 256), 256, 0, stream>>>(
            mat, row, col, out);
    }
}

// Round 5
// 171.507 us; speedup vs baseline: 6.7855x; 1.0537x over previous
//
#include <hip/hip_runtime.h>

// COO scatter-add: out[row[i], :] += mat[col[i], :]
// NC=NT=100000, NNZ=640000, D=128, fp32.
// Strategy: XCD-partitioned fixed-capacity row buckets -> segment sum.
// Rows split into 8 ranges of 12500; block group (blockIdx%8) handles one
// range so each row's one-line bucket stays hot in a single XCD's L2
// (kills the write-allocate amplification of the random 4B scatter).

#define NC_CONST 100000
#define NNZ_CONST 640000
#define D_CONST 128
#define OVF_MAX 65536
#define NXCD 8
#define RANGE 12500              // NC / NXCD exactly
#define PLACE_BLOCKS 1024        // multiple of NXCD; 128 blocks per range
#define SCAN_BLK 256
#define NBLK ((NC_CONST + SCAN_BLK - 1) / SCAN_BLK)

typedef float v4f __attribute__((ext_vector_type(4)));

// ------- placement: each group of blocks scans all entries, keeps its range
template <int CAP>
__global__ __launch_bounds__(256) void place_xcd_kernel(
    const int* __restrict__ row, const int* __restrict__ col,
    int* __restrict__ cnt, int* __restrict__ ovf_cnt,
    int* __restrict__ ovf, int* __restrict__ bucket) {
    const int xcd = blockIdx.x % NXCD;          // row-range id (XCD swizzle)
    const int gidx = blockIdx.x / NXCD;         // block index within group
    const int lo = xcd * RANGE;
    const int hi = lo + RANGE;                  // NC = 8*12500 exactly
    const int nthreads = (PLACE_BLOCKS / NXCD) * 256;

    for (int i = gidx * 256 + threadIdx.x; i < NNZ_CONST; i += nthreads) {
        int r = row[i];
        if (r >= lo && r < hi) {
            int c = col[i];
            int idx = atomicAdd(&cnt[r], 1);
            if (idx < CAP) {
                bucket[(size_t)r * CAP + idx] = c;
            } else {
                int o = atomicAdd(ovf_cnt, 1);
                if (o < OVF_MAX) { ovf[2 * o] = r; ovf[2 * o + 1] = c; }
            }
        }
    }
}

// ------- segment sum: one 32-lane group per row, same %8 row swizzle -----
template <int CAP>
__global__ __launch_bounds__(256) void segsum_xcd_kernel(
    const float* __restrict__ mat, const int* __restrict__ cnt,
    const int* __restrict__ ovf_cnt, const int* __restrict__ ovf,
    const int* __restrict__ bucket, float* __restrict__ out) {
    const int xcd = blockIdx.x % NXCD;
    const int local = blockIdx.x / NXCD;        // 0 .. ceil(RANGE/8)-1
    int g = xcd * RANGE + local * 8 + (threadIdx.x >> 5);
    int lane = threadIdx.x & 31;
    if (g >= xcd * RANGE + RANGE) return;

    int n = cnt[g];
    if (n > CAP) n = CAP;

    int myc = (lane < n) ? bucket[(size_t)g * CAP + lane] : 0;

    float ax = 0.f, ay = 0.f, az = 0.f, aw = 0.f;
    for (int j = 0; j < n; ++j) {
        int c = __shfl(myc, j, 32);
        const float4 v =
            reinterpret_cast<const float4*>(mat + (size_t)c * D_CONST)[lane];
        ax += v.x; ay += v.y; az += v.z; aw += v.w;
    }

    // overflow entries (effectively never at CAP=32, but correct)
    int novf = *ovf_cnt;
    if (novf > OVF_MAX) novf = OVF_MAX;
    for (int o = 0; o < novf; ++o) {
        if (ovf[2 * o] == g) {
            int c = ovf[2 * o + 1];
            const float4 v =
                reinterpret_cast<const float4*>(mat + (size_t)c * D_CONST)[lane];
            ax += v.x; ay += v.y; az += v.z; aw += v.w;
        }
    }

    v4f r;
    r.x = ax; r.y = ay; r.z = az; r.w = aw;
    __builtin_nontemporal_store(
        r, reinterpret_cast<v4f*>(out + (size_t)g * D_CONST) + lane);
}

// ================== fallback tier: full counting sort ====================
__global__ __launch_bounds__(256) void hist_kernel(
    const int* __restrict__ row, int* __restrict__ cnt) {
    int i = blockIdx.x * blockDim.x + threadIdx.x;
    if (i < NNZ_CONST) atomicAdd(&cnt[row[i]], 1);
}

__global__ __launch_bounds__(SCAN_BLK) void scan_reduce_kernel(
    const int* __restrict__ cnt, int* __restrict__ blocksums) {
    __shared__ int lds[SCAN_BLK];
    int i = blockIdx.x * SCAN_BLK + threadIdx.x;
    int v = (i < NC_CONST) ? cnt[i] : 0;
    lds[threadIdx.x] = v;
    __syncthreads();
    for (int s = SCAN_BLK / 2; s > 0; s >>= 1) {
        if (threadIdx.x < s) lds[threadIdx.x] += lds[threadIdx.x + s];
        __syncthreads();
    }
    if (threadIdx.x == 0) blocksums[blockIdx.x] = lds[0];
}

__global__ __launch_bounds__(512) void scan_spine_kernel(
    const int* __restrict__ blocksums, int* __restrict__ blockoffs) {
    __shared__ int lds[512];
    int t = threadIdx.x;
    int v = (t < NBLK) ? blocksums[t] : 0;
    lds[t] = v;
    __syncthreads();
    for (int s = 1; s < 512; s <<= 1) {
        int add = (t >= s) ? lds[t - s] : 0;
        __syncthreads();
        lds[t] += add;
        __syncthreads();
    }
    if (t < NBLK) blockoffs[t] = lds[t] - v;
}

__global__ __launch_bounds__(SCAN_BLK) void scan_final_kernel(
    const int* __restrict__ cnt, const int* __restrict__ blockoffs,
    int* __restrict__ offs, int* __restrict__ cursor) {
    __shared__ int lds[SCAN_BLK];
    int i = blockIdx.x * SCAN_BLK + threadIdx.x;
    int t = threadIdx.x;
    int v = (i < NC_CONST) ? cnt[i] : 0;
    lds[t] = v;
    __syncthreads();
    for (int s = 1; s < SCAN_BLK; s <<= 1) {
        int add = (t >= s) ? lds[t - s] : 0;
        __syncthreads();
        lds[t] += add;
        __syncthreads();
    }
    int off = blockoffs[blockIdx.x] + lds[t] - v;
    if (i < NC_CONST) {
        offs[i] = off;
        cursor[i] = off;
        if (i == NC_CONST - 1) offs[NC_CONST] = off + v;
    }
}

__global__ __launch_bounds__(256) void place_kernel(
    const int* __restrict__ row, const int* __restrict__ col,
    int* __restrict__ cursor, int* __restrict__ sorted_col) {
    int i = blockIdx.x * blockDim.x + threadIdx.x;
    if (i < NNZ_CONST) {
        int p = atomicAdd(&cursor[row[i]], 1);
        sorted_col[p] = col[i];
    }
}

__global__ __launch_bounds__(256) void segsum_kernel(
    const float* __restrict__ mat, const int* __restrict__ offs,
    const int* __restrict__ sorted_col, float* __restrict__ out) {
    int g = blockIdx.x * 8 + (threadIdx.x >> 5);
    int lane = threadIdx.x & 31;
    if (g >= NC_CONST) return;
    int beg = offs[g];
    int end = offs[g + 1];
    float ax = 0.f, ay = 0.f, az = 0.f, aw = 0.f;
    for (int j = beg; j < end; ++j) {
        int c = sorted_col[j];
        const float4 v =
            reinterpret_cast<const float4*>(mat + (size_t)c * D_CONST)[lane];
        ax += v.x; ay += v.y; az += v.z; aw += v.w;
    }
    float4 r; r.x = ax; r.y = ay; r.z = az; r.w = aw;
    reinterpret_cast<float4*>(out + (size_t)g * D_CONST)[lane] = r;
}

__global__ __launch_bounds__(256) void scatter_add_kernel(
    const float* __restrict__ mat, const int* __restrict__ row,
    const int* __restrict__ col, float* __restrict__ out) {
    int gid = blockIdx.x * blockDim.x + threadIdx.x;
    int nz = gid >> 5;
    int lane = gid & 31;
    if (nz >= NNZ_CONST) return;
    int r = row[nz];
    int c = col[nz];
    const float4 v =
        reinterpret_cast<const float4*>(mat + (size_t)c * D_CONST)[lane];
    float* o = out + (size_t)r * D_CONST + (size_t)lane * 4;
    atomicAdd(o + 0, v.x);
    atomicAdd(o + 1, v.y);
    atomicAdd(o + 2, v.z);
    atomicAdd(o + 3, v.w);
}

// =========================================================================
template <int CAP>
static void launch_bucket_path(const float* mat, const int* row, const int* col,
                               float* out, void* d_ws, hipStream_t stream) {
    int* cnt     = (int*)d_ws;               // NC
    int* ovf_cnt = cnt + NC_CONST;           // 1
    int* ovf     = ovf_cnt + 1;              // 2*OVF_MAX
    int* bucket  = ovf + 2 * OVF_MAX;        // NC*CAP

    (void)hipMemsetAsync(cnt, 0, (size_t)(NC_CONST + 1) * sizeof(int), stream);

    place_xcd_kernel<CAP><<<PLACE_BLOCKS, 256, 0, stream>>>(
        row, col, cnt, ovf_cnt, ovf, bucket);

    const int seg_blocks = ((RANGE + 7) / 8) * NXCD;
    segsum_xcd_kernel<CAP><<<seg_blocks, 256, 0, stream>>>(
        mat, cnt, ovf_cnt, ovf, bucket, out);
}

extern "C" void kernel_launch(void* const* d_in, const int* in_sizes, int n_in,
                              void* d_out, int out_size, void* d_ws, size_t ws_size,
                              hipStream_t stream) {
    const float* mat = (const float*)d_in[0];
    const int* row   = (const int*)d_in[1];
    const int* col   = (const int*)d_in[2];
    float* out = (float*)d_out;

    const size_t need32 =
        (size_t)(NC_CONST + 1 + 2 * OVF_MAX + (size_t)NC_CONST * 32) * sizeof(int);
    const size_t need16 =
        (size_t)(NC_CONST + 1 + 2 * OVF_MAX + (size_t)NC_CONST * 16) * sizeof(int);
    const size_t need_sort =
        (size_t)(NC_CONST + NC_CONST + 1 + NC_CONST + NNZ_CONST + 2 * NBLK) *
        sizeof(int);

    if (ws_size >= need32) {
        launch_bucket_path<32>(mat, row, col, out, d_ws, stream);
    } else if (ws_size >= need16) {
        launch_bucket_path<16>(mat, row, col, out, d_ws, stream);
    } else if (ws_size >= need_sort) {
        int* cnt        = (int*)d_ws;
        int* offs       = cnt + NC_CONST;
        int* cursor     = offs + NC_CONST + 1;
        int* sorted_col = cursor + NC_CONST;
        int* blocksums  = sorted_col + NNZ_CONST;
        int* blockoffs  = blocksums + NBLK;

        (void)hipMemsetAsync(cnt, 0, (size_t)NC_CONST * sizeof(int), stream);
        hist_kernel<<<(NNZ_CONST + 255) / 256, 256, 0, stream>>>(row, cnt);
        scan_reduce_kernel<<<NBLK, SCAN_BLK, 0, stream>>>(cnt, blocksums);
        scan_spine_kernel<<<1, 512, 0, stream>>>(blocksums, blockoffs);
        scan_final_kernel<<<NBLK, SCAN_BLK, 0, stream>>>(cnt, blockoffs, offs, cursor);
        place_kernel<<<(NNZ_CONST + 255) / 256, 256, 0, stream>>>(row, col, cursor, sorted_col);
        segsum_kernel<<<(NC_CONST + 7) / 8, 256, 0, stream>>>(mat, offs, sorted_col, out);
    } else {
        (void)hipMemsetAsync(out, 0, (size_t)out_size * sizeof(float), stream);
        const long long total = (long long)NNZ_CONST * 32;
        scatter_add_kernel<<<(int)((total + 255) / 256), 256, 0, stream>>>(
            mat, row, col, out);
    }
}